// Round 4
// baseline (645.330 us; speedup 1.0000x reference)
//
#include <hip/hip_runtime.h>

typedef __bf16 bf16_t;
typedef __attribute__((ext_vector_type(8))) __bf16 bf16x8;
typedef __attribute__((ext_vector_type(4))) float f32x4;

#define NH   8
#define DH   64
#define DD   512
#define NPIX 65536   // 256*256

__device__ __forceinline__ unsigned short f2bf(float f) {
  unsigned int u = __builtin_bit_cast(unsigned int, f);
  u += 0x7fffu + ((u >> 16) & 1u);
  return (unsigned short)(u >> 16);
}
__device__ __forceinline__ float bf2f(unsigned short b) {
  return __builtin_bit_cast(float, ((unsigned int)b) << 16);
}

__device__ __forceinline__ void gload_lds16(const void* g, void* l) {
  __builtin_amdgcn_global_load_lds(
      (const __attribute__((address_space(1))) void*)(uintptr_t)g,
      (__attribute__((address_space(3))) void*)(uintptr_t)l, 16, 0, 0);
}

// ---------------- elementwise fp32 -> bf16 convert (weights) ----------------
__global__ __launch_bounds__(256) void k_cvt(const float* __restrict__ in,
                                             unsigned short* __restrict__ out, int n4) {
  int i = blockIdx.x * 256 + threadIdx.x;
  if (i >= n4) return;
  float4 v = ((const float4*)in)[i];
  ushort4 o; o.x = f2bf(v.x); o.y = f2bf(v.y); o.z = f2bf(v.z); o.w = f2bf(v.w);
  ((ushort4*)out)[i] = o;
}

// ------------- x [512][65536] f32 -> x^T [65536][512] bf16 ------------------
__global__ __launch_bounds__(256) void k_cvt_transpose(const float* __restrict__ x,
                                                       unsigned short* __restrict__ xt) {
  __shared__ unsigned short Xs[64 * 68];
  int p0 = blockIdx.x * 64, c0 = blockIdx.y * 64;
  int t = threadIdx.x;
  for (int rep = 0; rep < 4; ++rep) {
    int f = rep * 256 + t, i = f >> 4, jj = f & 15;
    float4 v = *(const float4*)(x + (size_t)(c0 + i) * NPIX + p0 + jj * 4);
    ushort4 o; o.x = f2bf(v.x); o.y = f2bf(v.y); o.z = f2bf(v.z); o.w = f2bf(v.w);
    *(ushort4*)(Xs + i * 68 + jj * 4) = o;
  }
  __syncthreads();
  int j = t >> 2, q = t & 3;
  unsigned short* dst = xt + (size_t)(p0 + j) * DD + c0 + q * 16;
  for (int h2 = 0; h2 < 2; ++h2) {
    union { unsigned short u[8]; uint4 v; } pk;
    for (int cc = 0; cc < 8; ++cc) pk.u[cc] = Xs[(q * 16 + h2 * 8 + cc) * 68 + j];
    *(uint4*)(dst + h2 * 8) = pk.v;
  }
}

// ---------------- GEMM: C[1536][65536] = W[1536][512] @ X + b ---------------
// 256x256 tile, BK=64, 8 waves (2Mx4N), 4 phases per K-tile:
//  P0: rdA(mh0)+rdB(nh0,A); MF(0,0)   P1: rdB(nh1,B); MF(0,1)
//  P2: rdA(mh1)+rdB(nh0,A); MF(1,1)   P3: STAGE(t+2)->buf cur; MF(1,0); vmcnt(8)
// After P2's barrier no wave reads buf cur again -> P3's stage is race-free.
__global__ __launch_bounds__(512, 2) void k_gemm(const unsigned short* __restrict__ A,
                                                 const unsigned short* __restrict__ Bt,
                                                 const float* __restrict__ bias,
                                                 unsigned short* __restrict__ qk_t,
                                                 unsigned short* __restrict__ v_nat) {
  __shared__ unsigned short smem[65536];  // 128 KiB: 2 x (A 256x64 + B 256x64) bf16
  int tid = threadIdx.x, lane = tid & 63, wave = tid >> 6;
  int lr = lane & 15, lq = lane >> 4;
  // T1: bijective XCD swizzle over 1536 blocks (1536 % 8 == 0)
  int bid = blockIdx.y * 6 + blockIdx.x;
  int lid = (bid & 7) * 192 + (bid >> 3);
  int M0 = (lid % 6) * 256;
  size_t N0 = (size_t)(lid / 6) * 256;
  int wr = wave >> 2, wc = wave & 3;   // 2 x 4 wave grid; wave tile 128x64
  f32x4 acc[8][4] = {};

  const unsigned short* Abase = A + (size_t)M0 * 512;
  const unsigned short* Bbase = Bt + N0 * 512;

  // stage tile kt into buffer b. LDS linear [256 rows][64 cols] bf16 (128B rows);
  // T2: source chunk pre-swizzled so reads can XOR ((row&7)<<4) conflict-free.
  auto STAGE = [&](int b, int kt) {
#pragma unroll
    for (int it = 0; it < 4; ++it) {
      int f = it * 512 + tid;
      int row = f >> 3;
      int cc = (f & 7) ^ (row & 7);
      const unsigned short* ga = Abase + (size_t)row * 512 + kt * 64 + cc * 8;
      gload_lds16(ga, smem + b * 32768 + f * 8);
      const unsigned short* gb = Bbase + (size_t)row * 512 + kt * 64 + cc * 8;
      gload_lds16(gb, smem + b * 32768 + 16384 + f * 8);
    }
  };

  bf16x8 af[2][4], bfrA[2][2], bfrB[2][2];

  // prologue: tiles 0,1 staged; wait tile0 (8 of tile1 stay in flight)
  STAGE(0, 0);
  STAGE(1, 1);
  asm volatile("s_waitcnt vmcnt(8)" ::: "memory");
  __builtin_amdgcn_s_barrier();
  __builtin_amdgcn_sched_barrier(0);

  int cur = 0;
  for (int t = 0; t < 8; ++t) {
    const char* Ad = (const char*)smem + cur * 65536;
    const char* Bd = Ad + 32768;

    auto RD_A = [&](int mh) {
#pragma unroll
      for (int ks = 0; ks < 2; ++ks)
#pragma unroll
        for (int mf = 0; mf < 4; ++mf) {
          int r = wr * 128 + mh * 64 + mf * 16 + lr;
          int c = ks * 64 + lq * 16;
          af[ks][mf] = *(const bf16x8*)(Ad + r * 128 + (c ^ ((r & 7) << 4)));
        }
    };
    auto RD_B = [&](int nh, bf16x8 (&bb)[2][2]) {
#pragma unroll
      for (int ks = 0; ks < 2; ++ks)
#pragma unroll
        for (int nf = 0; nf < 2; ++nf) {
          int r = wc * 64 + nh * 32 + nf * 16 + lr;
          int c = ks * 64 + lq * 16;
          bb[ks][nf] = *(const bf16x8*)(Bd + r * 128 + (c ^ ((r & 7) << 4)));
        }
    };
    auto MF = [&](int mh, int nh, bf16x8 (&bb)[2][2]) {
      __builtin_amdgcn_s_setprio(1);
#pragma unroll
      for (int ks = 0; ks < 2; ++ks)
#pragma unroll
        for (int mf = 0; mf < 4; ++mf)
#pragma unroll
          for (int nf = 0; nf < 2; ++nf)
            acc[mh * 4 + mf][nh * 2 + nf] = __builtin_amdgcn_mfma_f32_16x16x32_bf16(
                af[ks][mf], bb[ks][nf], acc[mh * 4 + mf][nh * 2 + nf], 0, 0, 0);
      __builtin_amdgcn_s_setprio(0);
    };

    // ---- P0 ----
    RD_A(0);
    RD_B(0, bfrA);
    MF(0, 0, bfrA);
    __builtin_amdgcn_s_barrier();
    __builtin_amdgcn_sched_barrier(0);
    // ---- P1 ----
    RD_B(1, bfrB);
    MF(0, 1, bfrB);
    __builtin_amdgcn_s_barrier();
    __builtin_amdgcn_sched_barrier(0);
    // ---- P2 ----  (last LDS reads of buf cur)
    RD_A(1);
    RD_B(0, bfrA);
    MF(1, 1, bfrB);
    __builtin_amdgcn_s_barrier();   // all waves done reading buf cur
    __builtin_amdgcn_sched_barrier(0);
    // ---- P3 ---- (register-only MFMA; stage t+2 into freed buf cur)
    if (t <= 5) STAGE(cur, t + 2);
    MF(1, 0, bfrA);
    if (t <= 5) {
      asm volatile("s_waitcnt vmcnt(8)" ::: "memory");  // tile t+1 landed; t+2 in flight
    } else if (t == 6) {
      asm volatile("s_waitcnt vmcnt(0)" ::: "memory");  // tile 7 landed
    }
    __builtin_amdgcn_s_barrier();
    __builtin_amdgcn_sched_barrier(0);
    cur ^= 1;
  }

  // bias add: C row m = M0 + wr*128 + mf*16 + lq*4 + r
#pragma unroll
  for (int mf = 0; mf < 8; ++mf) {
    f32x4 bv = *(const f32x4*)(bias + M0 + wr * 128 + mf * 16 + lq * 4);
#pragma unroll
    for (int nf = 0; nf < 4; ++nf) acc[mf][nf] += bv;
  }

  __syncthreads();  // full drain before smem reuse
  if (M0 < 1024) {
    // q/k: transposed store via LDS, two n-halves. Ct[128 n][264 m-stride]
    unsigned short* Ct = smem;
    for (int h2 = 0; h2 < 2; ++h2) {
      __syncthreads();
      if ((wc >> 1) == h2) {
        int ncb = (wc & 1) * 64;
#pragma unroll
        for (int mf = 0; mf < 8; ++mf)
#pragma unroll
          for (int nf = 0; nf < 4; ++nf) {
            int n = ncb + nf * 16 + lr;
            int m = wr * 128 + mf * 16 + lq * 4;
            ushort4 pk;
            pk.x = f2bf(acc[mf][nf].x); pk.y = f2bf(acc[mf][nf].y);
            pk.z = f2bf(acc[mf][nf].z); pk.w = f2bf(acc[mf][nf].w);
            *(ushort4*)(Ct + n * 264 + m) = pk;
          }
      }
      __syncthreads();
      int n = tid >> 2, q = tid & 3;
      const unsigned short* src = Ct + n * 264 + q * 64;
      unsigned short* dst = qk_t + (N0 + h2 * 128 + n) * 1024 + M0 + q * 64;
#pragma unroll
      for (int ch = 0; ch < 8; ++ch)
        *(uint4*)(dst + ch * 8) = *(const uint4*)(src + ch * 8);
    }
  } else {
    // v: natural layout, scalar stores (16 lanes -> 32B contiguous, L2 combines)
#pragma unroll
    for (int mf = 0; mf < 8; ++mf)
#pragma unroll
      for (int nf = 0; nf < 4; ++nf) {
        int m = M0 - 1024 + wr * 128 + mf * 16 + lq * 4;
        size_t n = N0 + wc * 64 + nf * 16 + lr;
#pragma unroll
        for (int r = 0; r < 4; ++r)
          v_nat[(size_t)(m + r) * NPIX + n] = f2bf(acc[mf][nf][r]);
      }
  }
}

// ---------------- attention: per (h, fixed, itile) block --------------------
// pixels p = fixed*256 + j. Block: 4 waves x 16 queries = 64 queries.
// S^T[j][i] = sum_c K^T[j][c] Q^T[i][c]; softmax over j; O[d][i] = sum_j V[d][j] P^T[j][i]
// T1 chunked-XCD swizzle: the 4 sibling i-tile blocks of one (h,fix) land on
// the same XCD so K/V staging hits L2 instead of HBM.
// PHASE 0: out1 = x + O (fp32, [D][S][L]) + bf16 transposed copy out_bt[p'][512]
// PHASE 1: out_bt[c][p'] = bf16(O)   (p' = fixed*256 + i)
template <int PHASE>
__global__ __launch_bounds__(256) void k_attn(const unsigned short* __restrict__ qk_t,
                                              const unsigned short* __restrict__ v_nat,
                                              const float* __restrict__ x,
                                              float* __restrict__ out1,
                                              unsigned short* __restrict__ out_bt) {
  __shared__ unsigned short smem[32768];      // 64 KiB
  unsigned short* Ks = smem;                  // 32 KiB: K^T [256][64] swz; later P
  unsigned short* Vs = smem + 16384;          // 32 KiB: V   [64][256] swz; later O^T
  int tid = threadIdx.x, lane = tid & 63, wave = tid >> 6;
  int lr = lane & 15, lq = lane >> 4;
  // chunked-XCD remap of the 8192-block grid (8192 = 8 XCD x 1024)
  int bid = blockIdx.x + 4 * blockIdx.y + 1024 * blockIdx.z;
  int lid = (bid & 7) * 1024 + (bid >> 3);
  int i0b = (lid & 3) * 64;
  int fix = (lid >> 2) & 255;
  int h = lid >> 10;
  size_t pixbase = (size_t)fix * 256;

  // stage K^T (rows j, 64 ch at col 512+h*64), XOR-swizzled
  {
    int jb = tid >> 3, ch = tid & 7;
    for (int iter = 0; iter < 8; ++iter) {
      int j = iter * 32 + jb;
      uint4 val = *(const uint4*)(qk_t + (pixbase + j) * 1024 + 512 + h * 64 + ch * 8);
      *(uint4*)((char*)Ks + j * 128 + ((ch * 16) ^ ((j & 7) << 4))) = val;
    }
    for (int iter = 0; iter < 8; ++iter) {  // stage V [64 d][256 j]
      int f = iter * 256 + tid, d = f >> 5, ch2 = f & 31;
      uint4 val = *(const uint4*)(v_nat + (size_t)(h * 64 + d) * NPIX + pixbase + ch2 * 8);
      *(uint4*)((char*)Vs + d * 512 + ((ch2 * 16) ^ ((d & 7) << 4))) = val;
    }
  }
  // Q fragments straight from global (B-operand: n=i=lr, k=c contiguous)
  const unsigned short* qp = qk_t + (pixbase + i0b + wave * 16 + lr) * 1024 + h * 64 + lq * 8;
  bf16x8 qf0 = *(const bf16x8*)(qp);
  bf16x8 qf1 = *(const bf16x8*)(qp + 32);
  __syncthreads();

  // S^T = K^T x Q  (lane holds S[j = mf*16 + lq*4 + r][i = lr])
  f32x4 s_acc[16] = {};
  __builtin_amdgcn_s_setprio(1);
  for (int mf = 0; mf < 16; ++mf) {
    int j = mf * 16 + lr;
    const char* krow = (const char*)Ks + j * 128;
    int swz = (j & 7) << 4;
    bf16x8 kf0 = *(const bf16x8*)(krow + ((lq * 16) ^ swz));
    bf16x8 kf1 = *(const bf16x8*)(krow + ((64 + lq * 16) ^ swz));
    s_acc[mf] = __builtin_amdgcn_mfma_f32_16x16x32_bf16(kf0, qf0, s_acc[mf], 0, 0, 0);
    s_acc[mf] = __builtin_amdgcn_mfma_f32_16x16x32_bf16(kf1, qf1, s_acc[mf], 0, 0, 0);
  }
  __builtin_amdgcn_s_setprio(0);
  // softmax over j: 64 in-lane values + xor16 + xor32
  float mx = -3.4e38f;
  for (int mf = 0; mf < 16; ++mf)
    for (int r = 0; r < 4; ++r) mx = fmaxf(mx, s_acc[mf][r]);
  mx = fmaxf(mx, __shfl_xor(mx, 16, 64));
  mx = fmaxf(mx, __shfl_xor(mx, 32, 64));
  float sum = 0.f;
  for (int mf = 0; mf < 16; ++mf)
    for (int r = 0; r < 4; ++r) {
      float p = __expf(s_acc[mf][r] - mx);
      s_acc[mf][r] = p; sum += p;
    }
  sum += __shfl_xor(sum, 16, 64);
  sum += __shfl_xor(sum, 32, 64);
  float inv = 1.f / sum;
  __syncthreads();  // everyone done reading Ks -> overlay P
  {
    char* Pw = (char*)Ks + wave * 8192;       // [16 i][256 j] bf16, swizzled
    int pswz = (lr & 7) << 4;
    for (int mf = 0; mf < 16; ++mf) {
      ushort4 pk;
      pk.x = f2bf(s_acc[mf][0] * inv); pk.y = f2bf(s_acc[mf][1] * inv);
      pk.z = f2bf(s_acc[mf][2] * inv); pk.w = f2bf(s_acc[mf][3] * inv);
      int jb = mf * 32 + lq * 8;              // byte offset of j0 within row
      *(ushort4*)(Pw + lr * 512 + (jb ^ pswz)) = pk;
    }
  }
  // PV: O[d][i] = V x P^T
  f32x4 o_acc[4] = {};
  {
    const char* Pw = (const char*)Ks + wave * 8192;
    int pswz = (lr & 7) << 4;
    __builtin_amdgcn_s_setprio(1);
    for (int ks = 0; ks < 8; ++ks) {
      bf16x8 pb = *(const bf16x8*)(Pw + lr * 512 + ((ks * 64 + lq * 16) ^ pswz));
      for (int mf = 0; mf < 4; ++mf) {
        int d = mf * 16 + lr;
        bf16x8 vf = *(const bf16x8*)((const char*)Vs + d * 512 + ((ks * 64 + lq * 16) ^ ((d & 7) << 4)));
        o_acc[mf] = __builtin_amdgcn_mfma_f32_16x16x32_bf16(vf, pb, o_acc[mf], 0, 0, 0);
      }
    }
    __builtin_amdgcn_s_setprio(0);
  }
  int i_loc = wave * 16 + lr;
  size_t i_glob = (size_t)i0b + i_loc;
  if (PHASE == 0) {
    float vres[4][4];
    for (int mf = 0; mf < 4; ++mf) {
      int dbase = mf * 16 + lq * 4;
      for (int r = 0; r < 4; ++r) {
        size_t off = (size_t)(h * 64 + dbase + r) * NPIX + pixbase + i_glob;
        float val = o_acc[mf][r] + x[off];
        out1[off] = val;
        vres[mf][r] = val;
      }
    }
    __syncthreads();                         // PV reads of Vs done -> overlay O^T
    unsigned short* Obt = Vs;                // [64 i][80 d]
    for (int mf = 0; mf < 4; ++mf) {
      int dbase = mf * 16 + lq * 4;
      ushort4 pk; pk.x = f2bf(vres[mf][0]); pk.y = f2bf(vres[mf][1]);
      pk.z = f2bf(vres[mf][2]); pk.w = f2bf(vres[mf][3]);
      *(ushort4*)(Obt + i_loc * 80 + dbase) = pk;
    }
    __syncthreads();
    int ii = tid >> 2, q = tid & 3;
    unsigned short* dst = out_bt + ((size_t)(i0b + ii) * 256 + fix) * 512 + h * 64 + q * 16;
    const unsigned short* src = Obt + ii * 80 + q * 16;
    *(uint4*)(dst)     = *(const uint4*)(src);
    *(uint4*)(dst + 8) = *(const uint4*)(src + 8);
  } else {
    for (int mf = 0; mf < 4; ++mf) {
      int dbase = mf * 16 + lq * 4;
      for (int r = 0; r < 4; ++r) {
        size_t off = (size_t)(h * 64 + dbase + r) * NPIX + pixbase + i_glob;
        out_bt[off] = f2bf(o_acc[mf][r]);
      }
    }
  }
}

// --------- final: out[c][s][l] += colout_bt[c][l][s] (LDS transpose-add) ----
__global__ __launch_bounds__(256) void k_final(const unsigned short* __restrict__ colt,
                                               float* __restrict__ out) {
  __shared__ unsigned short Xs[64 * 68];
  int c = blockIdx.y;
  int lt = blockIdx.x & 3, st = blockIdx.x >> 2;
  int l0 = lt * 64, s0 = st * 64;
  int t = threadIdx.x;
  for (int rep = 0; rep < 4; ++rep) {
    int f = rep * 256 + t, li = f >> 4, jj = f & 15;
    ushort4 v = *(const ushort4*)(colt + (size_t)c * NPIX + (size_t)(l0 + li) * 256 + s0 + jj * 4);
    *(ushort4*)(Xs + li * 68 + jj * 4) = v;
  }
  __syncthreads();
  int si = t >> 2, q = t & 3;
  float* drow = out + (size_t)c * NPIX + (size_t)(s0 + si) * 256 + l0 + q * 16;
  for (int h4 = 0; h4 < 4; ++h4) {
    float4 a = *(float4*)(drow + h4 * 4);
    a.x += bf2f(Xs[(q * 16 + h4 * 4 + 0) * 68 + si]);
    a.y += bf2f(Xs[(q * 16 + h4 * 4 + 1) * 68 + si]);
    a.z += bf2f(Xs[(q * 16 + h4 * 4 + 2) * 68 + si]);
    a.w += bf2f(Xs[(q * 16 + h4 * 4 + 3) * 68 + si]);
    *(float4*)(drow + h4 * 4) = a;
  }
}

extern "C" void kernel_launch(void* const* d_in, const int* in_sizes, int n_in,
                              void* d_out, int out_size, void* d_ws, size_t ws_size,
                              hipStream_t stream) {
  const float* x  = (const float*)d_in[0];
  const float* Wr = (const float*)d_in[1];
  const float* br = (const float*)d_in[2];
  const float* Wc = (const float*)d_in[3];
  const float* bc = (const float*)d_in[4];
  float* out = (float*)d_out;
  char* ws = (char*)d_ws;
  // workspace layout (~259 MB total)
  unsigned short* qk_t  = (unsigned short*)(ws);                            // 128 MB [65536][1024]
  unsigned short* v_nat = (unsigned short*)(ws + 134217728);                // 64 MB  [512][65536]
  unsigned short* scr3  = (unsigned short*)(ws + 134217728 + 67108864);     // 64 MB  x^T / out1bt / colout
  unsigned short* Wrb   = (unsigned short*)(ws + 268435456);                // 1.5 MB
  unsigned short* Wcb   = (unsigned short*)(ws + 268435456 + 1572864);      // 1.5 MB

  k_cvt<<<768, 256, 0, stream>>>(Wr, Wrb, 196608);
  k_cvt<<<768, 256, 0, stream>>>(Wc, Wcb, 196608);
  k_cvt_transpose<<<dim3(1024, 8), 256, 0, stream>>>(x, scr3);              // scr3 = x^T bf16
  k_gemm<<<dim3(6, 256), 512, 0, stream>>>(Wrb, scr3, br, qk_t, v_nat);     // row QKV
  k_attn<0><<<dim3(4, 256, 8), 256, 0, stream>>>(qk_t, v_nat, x, out, scr3);// out=out1, scr3=out1^T bf16
  k_gemm<<<dim3(6, 256), 512, 0, stream>>>(Wcb, scr3, bc, qk_t, v_nat);     // col QKV
  k_attn<1><<<dim3(4, 256, 8), 256, 0, stream>>>(qk_t, v_nat, nullptr, nullptr, scr3); // scr3=colout
  k_final<<<dim3(16, 512), 256, 0, stream>>>(scr3, out);                    // out += colout^T
}

// Round 5
// 627.041 us; speedup vs baseline: 1.0292x; 1.0292x over previous
//
#include <hip/hip_runtime.h>

typedef __bf16 bf16_t;
typedef __attribute__((ext_vector_type(8))) __bf16 bf16x8;
typedef __attribute__((ext_vector_type(4))) float f32x4;

#define NH   8
#define DH   64
#define DD   512
#define NPIX 65536   // 256*256

__device__ __forceinline__ unsigned short f2bf(float f) {
  unsigned int u = __builtin_bit_cast(unsigned int, f);
  u += 0x7fffu + ((u >> 16) & 1u);
  return (unsigned short)(u >> 16);
}
__device__ __forceinline__ float bf2f(unsigned short b) {
  return __builtin_bit_cast(float, ((unsigned int)b) << 16);
}

__device__ __forceinline__ void gload_lds16(const void* g, void* l) {
  __builtin_amdgcn_global_load_lds(
      (const __attribute__((address_space(1))) void*)(uintptr_t)g,
      (__attribute__((address_space(3))) void*)(uintptr_t)l, 16, 0, 0);
}

// ---------------- elementwise fp32 -> bf16 convert (weights) ----------------
__global__ __launch_bounds__(256) void k_cvt(const float* __restrict__ in,
                                             unsigned short* __restrict__ out, int n4) {
  int i = blockIdx.x * 256 + threadIdx.x;
  if (i >= n4) return;
  float4 v = ((const float4*)in)[i];
  ushort4 o; o.x = f2bf(v.x); o.y = f2bf(v.y); o.z = f2bf(v.z); o.w = f2bf(v.w);
  ((ushort4*)out)[i] = o;
}

// ------------- x [512][65536] f32 -> x^T [65536][512] bf16 ------------------
__global__ __launch_bounds__(256) void k_cvt_transpose(const float* __restrict__ x,
                                                       unsigned short* __restrict__ xt) {
  __shared__ unsigned short Xs[64 * 68];
  int p0 = blockIdx.x * 64, c0 = blockIdx.y * 64;
  int t = threadIdx.x;
  for (int rep = 0; rep < 4; ++rep) {
    int f = rep * 256 + t, i = f >> 4, jj = f & 15;
    float4 v = *(const float4*)(x + (size_t)(c0 + i) * NPIX + p0 + jj * 4);
    ushort4 o; o.x = f2bf(v.x); o.y = f2bf(v.y); o.z = f2bf(v.z); o.w = f2bf(v.w);
    *(ushort4*)(Xs + i * 68 + jj * 4) = o;
  }
  __syncthreads();
  int j = t >> 2, q = t & 3;
  unsigned short* dst = xt + (size_t)(p0 + j) * DD + c0 + q * 16;
  for (int h2 = 0; h2 < 2; ++h2) {
    union { unsigned short u[8]; uint4 v; } pk;
    for (int cc = 0; cc < 8; ++cc) pk.u[cc] = Xs[(q * 16 + h2 * 8 + cc) * 68 + j];
    *(uint4*)(dst + h2 * 8) = pk.v;
  }
}

// ---------------- GEMM: C[1536][65536] = W[1536][512] @ X + b ---------------
// 256x256 tile, BK=64, 8 waves (2Mx4N), m201-style 8-phase schedule:
// per phase: {ds_reads; stage <=1 half; [lgkm(8)]; barrier; lgkm(0); setprio;
//             16 MFMA; setprio; [vmcnt at k3/k7]; barrier}
// Stage ledger (tile t+2 into buf t&1): B0@4t+2, A0@4t+3, B1@4t+4, A1@4t+5.
// B region free after tile-phase1-close; A after tile-phase2-close. vmcnt(4)
// at each 4t+3 (2 halves = 4 loads in flight).
__global__ __launch_bounds__(512, 2) void k_gemm(const unsigned short* __restrict__ A,
                                                 const unsigned short* __restrict__ Bt,
                                                 const float* __restrict__ bias,
                                                 unsigned short* __restrict__ qk_t,
                                                 unsigned short* __restrict__ v_nat) {
  __shared__ unsigned short smem[65536];  // 128 KiB: 2 bufs x (A 256x64 + B 256x64)
  int tid = threadIdx.x, lane = tid & 63, wave = tid >> 6;
  int lr = lane & 15, lq = lane >> 4;
  // T1: bijective XCD swizzle over 1536 blocks (1536 % 8 == 0)
  int bid = blockIdx.y * 6 + blockIdx.x;
  int lid = (bid & 7) * 192 + (bid >> 3);
  int M0 = (lid % 6) * 256;
  size_t N0 = (size_t)(lid / 6) * 256;
  int wr = wave >> 2, wc = wave & 3;   // 2 x 4 wave grid; wave tile 128x64
  f32x4 acc[8][4] = {};

  const unsigned short* Abase = A + (size_t)M0 * 512;
  const unsigned short* Bbase = Bt + N0 * 512;

  // stage one half (mat: 0=A,1=B; h: 0/1 = rows h*128..; tile kt) into buf kt&1
  auto STH = [&](int mat, int h, int kt) {
    unsigned short* lbase = smem + (kt & 1) * 32768 + mat * 16384 + h * 8192;
    const unsigned short* gbase = (mat ? Bbase : Abase) + ((size_t)h * 128) * 512 + kt * 64;
#pragma unroll
    for (int it = 0; it < 2; ++it) {
      int f = it * 512 + tid;
      int row = f >> 3;
      int cc = (f & 7) ^ (row & 7);
      gload_lds16(gbase + (size_t)row * 512 + cc * 8, lbase + f * 8);
    }
  };

  bf16x8 af[2][4], bbA[2][2], bbB[2][2];
  auto RD_A = [&](int b, int mh) {
    const char* Ad = (const char*)(smem + b * 32768);
#pragma unroll
    for (int ks = 0; ks < 2; ++ks)
#pragma unroll
      for (int mf = 0; mf < 4; ++mf) {
        int r = wr * 128 + mh * 64 + mf * 16 + lr;
        int c = ks * 64 + lq * 16;
        af[ks][mf] = *(const bf16x8*)(Ad + r * 128 + (c ^ ((r & 7) << 4)));
      }
  };
  auto RD_B = [&](int b, int nh, bf16x8 (&bb)[2][2]) {
    const char* Bd = (const char*)(smem + b * 32768 + 16384);
#pragma unroll
    for (int ks = 0; ks < 2; ++ks)
#pragma unroll
      for (int nf = 0; nf < 2; ++nf) {
        int r = wc * 64 + nh * 32 + nf * 16 + lr;
        int c = ks * 64 + lq * 16;
        bb[ks][nf] = *(const bf16x8*)(Bd + r * 128 + (c ^ ((r & 7) << 4)));
      }
  };
  auto MF = [&](int mh, int nh, bf16x8 (&bb)[2][2]) {
    __builtin_amdgcn_s_setprio(1);
#pragma unroll
    for (int ks = 0; ks < 2; ++ks)
#pragma unroll
      for (int mf = 0; mf < 4; ++mf)
#pragma unroll
        for (int nf = 0; nf < 2; ++nf)
          acc[mh * 4 + mf][nh * 2 + nf] = __builtin_amdgcn_mfma_f32_16x16x32_bf16(
              af[ks][mf], bb[ks][nf], acc[mh * 4 + mf][nh * 2 + nf], 0, 0, 0);
    __builtin_amdgcn_s_setprio(0);
  };
  auto MIDBAR = [&]() {
    __builtin_amdgcn_s_barrier();
    asm volatile("s_waitcnt lgkmcnt(0)" ::: "memory");
    __builtin_amdgcn_sched_barrier(0);
  };
  auto ENDBAR = [&]() {
    __builtin_amdgcn_s_barrier();
    __builtin_amdgcn_sched_barrier(0);
  };

  // prologue: tiles 0 then 1 (8 loads each); wait tile0, tile1 stays in flight
  STH(0, 0, 0); STH(0, 1, 0); STH(1, 0, 0); STH(1, 1, 0);
  STH(0, 0, 1); STH(0, 1, 1); STH(1, 0, 1); STH(1, 1, 1);
  asm volatile("s_waitcnt vmcnt(8)" ::: "memory");
  __builtin_amdgcn_s_barrier();
  __builtin_amdgcn_sched_barrier(0);

#pragma unroll
  for (int i = 0; i < 4; ++i) {
    const int t0 = 2 * i, t1 = 2 * i + 1;
    const int b0 = 0, b1 = 1;
    // ---- k0: tile t0 quad(0,0); stage B1(t1) [i>0] ----
    RD_A(b0, 0); RD_B(b0, 0, bbA);
    if (i > 0) STH(1, 1, t1);
    asm volatile("s_waitcnt lgkmcnt(8)" ::: "memory");
    MIDBAR();
    MF(0, 0, bbA);
    ENDBAR();
    // ---- k1: quad(0,1); stage A1(t1) [i>0] ----
    RD_B(b0, 1, bbB);
    if (i > 0) STH(0, 1, t1);
    MIDBAR();
    MF(0, 1, bbB);
    ENDBAR();
    // ---- k2: quad(1,1); stage B0(t0+2) [i<3] ----
    RD_A(b0, 1);
    if (i < 3) STH(1, 0, t0 + 2);
    MIDBAR();
    MF(1, 1, bbB);
    ENDBAR();
    // ---- k3: quad(1,0) reg-only; stage A0(t0+2) [i<3]; vmcnt ----
    if (i < 3) STH(0, 0, t0 + 2);
    MIDBAR();
    MF(1, 0, bbA);
    if (i < 3) { asm volatile("s_waitcnt vmcnt(4)" ::: "memory"); }
    else       { asm volatile("s_waitcnt vmcnt(0)" ::: "memory"); }
    ENDBAR();
    // ---- k4: tile t1 quad(0,0); stage B1(t0+2) [i<3] ----
    RD_A(b1, 0); RD_B(b1, 0, bbA);
    if (i < 3) STH(1, 1, t0 + 2);
    asm volatile("s_waitcnt lgkmcnt(8)" ::: "memory");
    MIDBAR();
    MF(0, 0, bbA);
    ENDBAR();
    // ---- k5: quad(0,1); stage A1(t0+2) [i<3] ----
    RD_B(b1, 1, bbB);
    if (i < 3) STH(0, 1, t0 + 2);
    MIDBAR();
    MF(0, 1, bbB);
    ENDBAR();
    // ---- k6: quad(1,1); stage B0(t1+2) [i<3] ----
    RD_A(b1, 1);
    if (i < 3) STH(1, 0, t1 + 2);
    MIDBAR();
    MF(1, 1, bbB);
    ENDBAR();
    // ---- k7: quad(1,0) reg-only; stage A0(t1+2) [i<3]; vmcnt ----
    if (i < 3) STH(0, 0, t1 + 2);
    MIDBAR();
    MF(1, 0, bbA);
    if (i < 3) { asm volatile("s_waitcnt vmcnt(4)" ::: "memory"); }
    ENDBAR();
  }

  // bias add: C row m = M0 + wr*128 + mf*16 + lq*4 + r
#pragma unroll
  for (int mf = 0; mf < 8; ++mf) {
    f32x4 bv = *(const f32x4*)(bias + M0 + wr * 128 + mf * 16 + lq * 4);
#pragma unroll
    for (int nf = 0; nf < 4; ++nf) acc[mf][nf] += bv;
  }

  __syncthreads();  // full drain before smem reuse
  if (M0 < 1024) {
    // q/k: transposed store via LDS, two n-halves. Ct[128 n][264 m-stride]
    unsigned short* Ct = smem;
    for (int h2 = 0; h2 < 2; ++h2) {
      __syncthreads();
      if ((wc >> 1) == h2) {
        int ncb = (wc & 1) * 64;
#pragma unroll
        for (int mf = 0; mf < 8; ++mf)
#pragma unroll
          for (int nf = 0; nf < 4; ++nf) {
            int n = ncb + nf * 16 + lr;
            int m = wr * 128 + mf * 16 + lq * 4;
            ushort4 pk;
            pk.x = f2bf(acc[mf][nf].x); pk.y = f2bf(acc[mf][nf].y);
            pk.z = f2bf(acc[mf][nf].z); pk.w = f2bf(acc[mf][nf].w);
            *(ushort4*)(Ct + n * 264 + m) = pk;
          }
      }
      __syncthreads();
      int n = tid >> 2, q = tid & 3;
      const unsigned short* src = Ct + n * 264 + q * 64;
      unsigned short* dst = qk_t + (N0 + h2 * 128 + n) * 1024 + M0 + q * 64;
#pragma unroll
      for (int ch = 0; ch < 8; ++ch)
        *(uint4*)(dst + ch * 8) = *(const uint4*)(src + ch * 8);
    }
  } else {
    // v: natural layout, scalar stores (16 lanes -> 32B contiguous, L2 combines)
#pragma unroll
    for (int mf = 0; mf < 8; ++mf)
#pragma unroll
      for (int nf = 0; nf < 4; ++nf) {
        int m = M0 - 1024 + wr * 128 + mf * 16 + lq * 4;
        size_t n = N0 + wc * 64 + nf * 16 + lr;
#pragma unroll
        for (int r = 0; r < 4; ++r)
          v_nat[(size_t)(m + r) * NPIX + n] = f2bf(acc[mf][nf][r]);
      }
  }
}

// ---------------- attention: per (h, fixed, itile) block --------------------
// pixels p = fixed*256 + j. Block: 4 waves x 16 queries = 64 queries.
// S^T[j][i] = sum_c K^T[j][c] Q^T[i][c]; softmax over j; O[d][i] = sum_j V[d][j] P^T[j][i]
// T1 chunked-XCD swizzle: the 4 sibling i-tile blocks of one (h,fix) land on
// the same XCD so K/V staging hits L2 instead of HBM.
// PHASE 0: out1 = x + O (fp32, [D][S][L]) + bf16 transposed copy out_bt[p'][512]
// PHASE 1: out_bt[c][p'] = bf16(O)   (p' = fixed*256 + i)
template <int PHASE>
__global__ __launch_bounds__(256) void k_attn(const unsigned short* __restrict__ qk_t,
                                              const unsigned short* __restrict__ v_nat,
                                              const float* __restrict__ x,
                                              float* __restrict__ out1,
                                              unsigned short* __restrict__ out_bt) {
  __shared__ unsigned short smem[32768];      // 64 KiB
  unsigned short* Ks = smem;                  // 32 KiB: K^T [256][64] swz; later P
  unsigned short* Vs = smem + 16384;          // 32 KiB: V   [64][256] swz; later O^T
  int tid = threadIdx.x, lane = tid & 63, wave = tid >> 6;
  int lr = lane & 15, lq = lane >> 4;
  // chunked-XCD remap of the 8192-block grid (8192 = 8 XCD x 1024)
  int bid = blockIdx.x + 4 * blockIdx.y + 1024 * blockIdx.z;
  int lid = (bid & 7) * 1024 + (bid >> 3);
  int i0b = (lid & 3) * 64;
  int fix = (lid >> 2) & 255;
  int h = lid >> 10;
  size_t pixbase = (size_t)fix * 256;

  // stage K^T (rows j, 64 ch at col 512+h*64), XOR-swizzled
  {
    int jb = tid >> 3, ch = tid & 7;
    for (int iter = 0; iter < 8; ++iter) {
      int j = iter * 32 + jb;
      uint4 val = *(const uint4*)(qk_t + (pixbase + j) * 1024 + 512 + h * 64 + ch * 8);
      *(uint4*)((char*)Ks + j * 128 + ((ch * 16) ^ ((j & 7) << 4))) = val;
    }
    for (int iter = 0; iter < 8; ++iter) {  // stage V [64 d][256 j]
      int f = iter * 256 + tid, d = f >> 5, ch2 = f & 31;
      uint4 val = *(const uint4*)(v_nat + (size_t)(h * 64 + d) * NPIX + pixbase + ch2 * 8);
      *(uint4*)((char*)Vs + d * 512 + ((ch2 * 16) ^ ((d & 7) << 4))) = val;
    }
  }
  // Q fragments straight from global (B-operand: n=i=lr, k=c contiguous)
  const unsigned short* qp = qk_t + (pixbase + i0b + wave * 16 + lr) * 1024 + h * 64 + lq * 8;
  bf16x8 qf0 = *(const bf16x8*)(qp);
  bf16x8 qf1 = *(const bf16x8*)(qp + 32);
  __syncthreads();

  // S^T = K^T x Q  (lane holds S[j = mf*16 + lq*4 + r][i = lr])
  f32x4 s_acc[16] = {};
  __builtin_amdgcn_s_setprio(1);
  for (int mf = 0; mf < 16; ++mf) {
    int j = mf * 16 + lr;
    const char* krow = (const char*)Ks + j * 128;
    int swz = (j & 7) << 4;
    bf16x8 kf0 = *(const bf16x8*)(krow + ((lq * 16) ^ swz));
    bf16x8 kf1 = *(const bf16x8*)(krow + ((64 + lq * 16) ^ swz));
    s_acc[mf] = __builtin_amdgcn_mfma_f32_16x16x32_bf16(kf0, qf0, s_acc[mf], 0, 0, 0);
    s_acc[mf] = __builtin_amdgcn_mfma_f32_16x16x32_bf16(kf1, qf1, s_acc[mf], 0, 0, 0);
  }
  __builtin_amdgcn_s_setprio(0);
  // softmax over j: 64 in-lane values + xor16 + xor32
  float mx = -3.4e38f;
  for (int mf = 0; mf < 16; ++mf)
    for (int r = 0; r < 4; ++r) mx = fmaxf(mx, s_acc[mf][r]);
  mx = fmaxf(mx, __shfl_xor(mx, 16, 64));
  mx = fmaxf(mx, __shfl_xor(mx, 32, 64));
  float sum = 0.f;
  for (int mf = 0; mf < 16; ++mf)
    for (int r = 0; r < 4; ++r) {
      float p = __expf(s_acc[mf][r] - mx);
      s_acc[mf][r] = p; sum += p;
    }
  sum += __shfl_xor(sum, 16, 64);
  sum += __shfl_xor(sum, 32, 64);
  float inv = 1.f / sum;
  __syncthreads();  // everyone done reading Ks -> overlay P
  {
    char* Pw = (char*)Ks + wave * 8192;       // [16 i][256 j] bf16, swizzled
    int pswz = (lr & 7) << 4;
    for (int mf = 0; mf < 16; ++mf) {
      ushort4 pk;
      pk.x = f2bf(s_acc[mf][0] * inv); pk.y = f2bf(s_acc[mf][1] * inv);
      pk.z = f2bf(s_acc[mf][2] * inv); pk.w = f2bf(s_acc[mf][3] * inv);
      int jb = mf * 32 + lq * 8;              // byte offset of j0 within row
      *(ushort4*)(Pw + lr * 512 + (jb ^ pswz)) = pk;
    }
  }
  // PV: O[d][i] = V x P^T
  f32x4 o_acc[4] = {};
  {
    const char* Pw = (const char*)Ks + wave * 8192;
    int pswz = (lr & 7) << 4;
    __builtin_amdgcn_s_setprio(1);
    for (int ks = 0; ks < 8; ++ks) {
      bf16x8 pb = *(const bf16x8*)(Pw + lr * 512 + ((ks * 64 + lq * 16) ^ pswz));
      for (int mf = 0; mf < 4; ++mf) {
        int d = mf * 16 + lr;
        bf16x8 vf = *(const bf16x8*)((const char*)Vs + d * 512 + ((ks * 64 + lq * 16) ^ ((d & 7) << 4)));
        o_acc[mf] = __builtin_amdgcn_mfma_f32_16x16x32_bf16(vf, pb, o_acc[mf], 0, 0, 0);
      }
    }
    __builtin_amdgcn_s_setprio(0);
  }
  int i_loc = wave * 16 + lr;
  size_t i_glob = (size_t)i0b + i_loc;
  if (PHASE == 0) {
    float vres[4][4];
    for (int mf = 0; mf < 4; ++mf) {
      int dbase = mf * 16 + lq * 4;
      for (int r = 0; r < 4; ++r) {
        size_t off = (size_t)(h * 64 + dbase + r) * NPIX + pixbase + i_glob;
        float val = o_acc[mf][r] + x[off];
        out1[off] = val;
        vres[mf][r] = val;
      }
    }
    __syncthreads();                         // PV reads of Vs done -> overlay O^T
    unsigned short* Obt = Vs;                // [64 i][80 d]
    for (int mf = 0; mf < 4; ++mf) {
      int dbase = mf * 16 + lq * 4;
      ushort4 pk; pk.x = f2bf(vres[mf][0]); pk.y = f2bf(vres[mf][1]);
      pk.z = f2bf(vres[mf][2]); pk.w = f2bf(vres[mf][3]);
      *(ushort4*)(Obt + i_loc * 80 + dbase) = pk;
    }
    __syncthreads();
    int ii = tid >> 2, q = tid & 3;
    unsigned short* dst = out_bt + ((size_t)(i0b + ii) * 256 + fix) * 512 + h * 64 + q * 16;
    const unsigned short* src = Obt + ii * 80 + q * 16;
    *(uint4*)(dst)     = *(const uint4*)(src);
    *(uint4*)(dst + 8) = *(const uint4*)(src + 8);
  } else {
    for (int mf = 0; mf < 4; ++mf) {
      int dbase = mf * 16 + lq * 4;
      for (int r = 0; r < 4; ++r) {
        size_t off = (size_t)(h * 64 + dbase + r) * NPIX + pixbase + i_glob;
        out_bt[off] = f2bf(o_acc[mf][r]);
      }
    }
  }
}

// --------- final: out[c][s][l] += colout_bt[c][l][s] (LDS transpose-add) ----
__global__ __launch_bounds__(256) void k_final(const unsigned short* __restrict__ colt,
                                               float* __restrict__ out) {
  __shared__ unsigned short Xs[64 * 68];
  int c = blockIdx.y;
  int lt = blockIdx.x & 3, st = blockIdx.x >> 2;
  int l0 = lt * 64, s0 = st * 64;
  int t = threadIdx.x;
  for (int rep = 0; rep < 4; ++rep) {
    int f = rep * 256 + t, li = f >> 4, jj = f & 15;
    ushort4 v = *(const ushort4*)(colt + (size_t)c * NPIX + (size_t)(l0 + li) * 256 + s0 + jj * 4);
    *(ushort4*)(Xs + li * 68 + jj * 4) = v;
  }
  __syncthreads();
  int si = t >> 2, q = t & 3;
  float* drow = out + (size_t)c * NPIX + (size_t)(s0 + si) * 256 + l0 + q * 16;
  for (int h4 = 0; h4 < 4; ++h4) {
    float4 a = *(float4*)(drow + h4 * 4);
    a.x += bf2f(Xs[(q * 16 + h4 * 4 + 0) * 68 + si]);
    a.y += bf2f(Xs[(q * 16 + h4 * 4 + 1) * 68 + si]);
    a.z += bf2f(Xs[(q * 16 + h4 * 4 + 2) * 68 + si]);
    a.w += bf2f(Xs[(q * 16 + h4 * 4 + 3) * 68 + si]);
    *(float4*)(drow + h4 * 4) = a;
  }
}

extern "C" void kernel_launch(void* const* d_in, const int* in_sizes, int n_in,
                              void* d_out, int out_size, void* d_ws, size_t ws_size,
                              hipStream_t stream) {
  const float* x  = (const float*)d_in[0];
  const float* Wr = (const float*)d_in[1];
  const float* br = (const float*)d_in[2];
  const float* Wc = (const float*)d_in[3];
  const float* bc = (const float*)d_in[4];
  float* out = (float*)d_out;
  char* ws = (char*)d_ws;
  // workspace layout (~259 MB total)
  unsigned short* qk_t  = (unsigned short*)(ws);                            // 128 MB [65536][1024]
  unsigned short* v_nat = (unsigned short*)(ws + 134217728);                // 64 MB  [512][65536]
  unsigned short* scr3  = (unsigned short*)(ws + 134217728 + 67108864);     // 64 MB  x^T / out1bt / colout
  unsigned short* Wrb   = (unsigned short*)(ws + 268435456);                // 1.5 MB
  unsigned short* Wcb   = (unsigned short*)(ws + 268435456 + 1572864);      // 1.5 MB

  k_cvt<<<768, 256, 0, stream>>>(Wr, Wrb, 196608);
  k_cvt<<<768, 256, 0, stream>>>(Wc, Wcb, 196608);
  k_cvt_transpose<<<dim3(1024, 8), 256, 0, stream>>>(x, scr3);              // scr3 = x^T bf16
  k_gemm<<<dim3(6, 256), 512, 0, stream>>>(Wrb, scr3, br, qk_t, v_nat);     // row QKV
  k_attn<0><<<dim3(4, 256, 8), 256, 0, stream>>>(qk_t, v_nat, x, out, scr3);// out=out1, scr3=out1^T bf16
  k_gemm<<<dim3(6, 256), 512, 0, stream>>>(Wcb, scr3, bc, qk_t, v_nat);     // col QKV
  k_attn<1><<<dim3(4, 256, 8), 256, 0, stream>>>(qk_t, v_nat, nullptr, nullptr, scr3); // scr3=colout
  k_final<<<dim3(16, 512), 256, 0, stream>>>(scr3, out);                    // out += colout^T
}

// Round 6
// 619.218 us; speedup vs baseline: 1.0422x; 1.0126x over previous
//
#include <hip/hip_runtime.h>

typedef __bf16 bf16_t;
typedef __attribute__((ext_vector_type(8))) __bf16 bf16x8;
typedef __attribute__((ext_vector_type(4))) float f32x4;
typedef __attribute__((ext_vector_type(16))) float f32x16;

#define NH   8
#define DH   64
#define DD   512
#define NPIX 65536   // 256*256

__device__ __forceinline__ unsigned short f2bf(float f) {
  unsigned int u = __builtin_bit_cast(unsigned int, f);
  u += 0x7fffu + ((u >> 16) & 1u);
  return (unsigned short)(u >> 16);
}
__device__ __forceinline__ float bf2f(unsigned short b) {
  return __builtin_bit_cast(float, ((unsigned int)b) << 16);
}
__device__ __forceinline__ unsigned cvtpk(float a, float b) {
  unsigned r;
  asm("v_cvt_pk_bf16_f32 %0, %1, %2" : "=v"(r) : "v"(a), "v"(b));
  return r;
}

__device__ __forceinline__ void gload_lds16(const void* g, void* l) {
  __builtin_amdgcn_global_load_lds(
      (const __attribute__((address_space(1))) void*)(uintptr_t)g,
      (__attribute__((address_space(3))) void*)(uintptr_t)l, 16, 0, 0);
}

// ---------------- elementwise fp32 -> bf16 convert (weights) ----------------
__global__ __launch_bounds__(256) void k_cvt(const float* __restrict__ in,
                                             unsigned short* __restrict__ out, int n4) {
  int i = blockIdx.x * 256 + threadIdx.x;
  if (i >= n4) return;
  float4 v = ((const float4*)in)[i];
  ushort4 o; o.x = f2bf(v.x); o.y = f2bf(v.y); o.z = f2bf(v.z); o.w = f2bf(v.w);
  ((ushort4*)out)[i] = o;
}

// ------------- x [512][65536] f32 -> x^T [65536][512] bf16 ------------------
__global__ __launch_bounds__(256) void k_cvt_transpose(const float* __restrict__ x,
                                                       unsigned short* __restrict__ xt) {
  __shared__ unsigned short Xs[64 * 68];
  int p0 = blockIdx.x * 64, c0 = blockIdx.y * 64;
  int t = threadIdx.x;
  for (int rep = 0; rep < 4; ++rep) {
    int f = rep * 256 + t, i = f >> 4, jj = f & 15;
    float4 v = *(const float4*)(x + (size_t)(c0 + i) * NPIX + p0 + jj * 4);
    ushort4 o; o.x = f2bf(v.x); o.y = f2bf(v.y); o.z = f2bf(v.z); o.w = f2bf(v.w);
    *(ushort4*)(Xs + i * 68 + jj * 4) = o;
  }
  __syncthreads();
  int j = t >> 2, q = t & 3;
  unsigned short* dst = xt + (size_t)(p0 + j) * DD + c0 + q * 16;
  for (int h2 = 0; h2 < 2; ++h2) {
    union { unsigned short u[8]; uint4 v; } pk;
    for (int cc = 0; cc < 8; ++cc) pk.u[cc] = Xs[(q * 16 + h2 * 8 + cc) * 68 + j];
    *(uint4*)(dst + h2 * 8) = pk.v;
  }
}

// ---------------- GEMM: C[1536][65536] = W[1536][512] @ X + b ---------------
// (R5 8-phase version, unchanged — passing at 156 us)
__global__ __launch_bounds__(512, 2) void k_gemm(const unsigned short* __restrict__ A,
                                                 const unsigned short* __restrict__ Bt,
                                                 const float* __restrict__ bias,
                                                 unsigned short* __restrict__ qk_t,
                                                 unsigned short* __restrict__ v_nat) {
  __shared__ unsigned short smem[65536];  // 128 KiB: 2 bufs x (A 256x64 + B 256x64)
  int tid = threadIdx.x, lane = tid & 63, wave = tid >> 6;
  int lr = lane & 15, lq = lane >> 4;
  int bid = blockIdx.y * 6 + blockIdx.x;
  int lid = (bid & 7) * 192 + (bid >> 3);
  int M0 = (lid % 6) * 256;
  size_t N0 = (size_t)(lid / 6) * 256;
  int wr = wave >> 2, wc = wave & 3;
  f32x4 acc[8][4] = {};

  const unsigned short* Abase = A + (size_t)M0 * 512;
  const unsigned short* Bbase = Bt + N0 * 512;

  auto STH = [&](int mat, int h, int kt) {
    unsigned short* lbase = smem + (kt & 1) * 32768 + mat * 16384 + h * 8192;
    const unsigned short* gbase = (mat ? Bbase : Abase) + ((size_t)h * 128) * 512 + kt * 64;
#pragma unroll
    for (int it = 0; it < 2; ++it) {
      int f = it * 512 + tid;
      int row = f >> 3;
      int cc = (f & 7) ^ (row & 7);
      gload_lds16(gbase + (size_t)row * 512 + cc * 8, lbase + f * 8);
    }
  };

  bf16x8 af[2][4], bbA[2][2], bbB[2][2];
  auto RD_A = [&](int b, int mh) {
    const char* Ad = (const char*)(smem + b * 32768);
#pragma unroll
    for (int ks = 0; ks < 2; ++ks)
#pragma unroll
      for (int mf = 0; mf < 4; ++mf) {
        int r = wr * 128 + mh * 64 + mf * 16 + lr;
        int c = ks * 64 + lq * 16;
        af[ks][mf] = *(const bf16x8*)(Ad + r * 128 + (c ^ ((r & 7) << 4)));
      }
  };
  auto RD_B = [&](int b, int nh, bf16x8 (&bb)[2][2]) {
    const char* Bd = (const char*)(smem + b * 32768 + 16384);
#pragma unroll
    for (int ks = 0; ks < 2; ++ks)
#pragma unroll
      for (int nf = 0; nf < 2; ++nf) {
        int r = wc * 64 + nh * 32 + nf * 16 + lr;
        int c = ks * 64 + lq * 16;
        bb[ks][nf] = *(const bf16x8*)(Bd + r * 128 + (c ^ ((r & 7) << 4)));
      }
  };
  auto MF = [&](int mh, int nh, bf16x8 (&bb)[2][2]) {
    __builtin_amdgcn_s_setprio(1);
#pragma unroll
    for (int ks = 0; ks < 2; ++ks)
#pragma unroll
      for (int mf = 0; mf < 4; ++mf)
#pragma unroll
        for (int nf = 0; nf < 2; ++nf)
          acc[mh * 4 + mf][nh * 2 + nf] = __builtin_amdgcn_mfma_f32_16x16x32_bf16(
              af[ks][mf], bb[ks][nf], acc[mh * 4 + mf][nh * 2 + nf], 0, 0, 0);
    __builtin_amdgcn_s_setprio(0);
  };
  auto MIDBAR = [&]() {
    __builtin_amdgcn_s_barrier();
    asm volatile("s_waitcnt lgkmcnt(0)" ::: "memory");
    __builtin_amdgcn_sched_barrier(0);
  };
  auto ENDBAR = [&]() {
    __builtin_amdgcn_s_barrier();
    __builtin_amdgcn_sched_barrier(0);
  };

  STH(0, 0, 0); STH(0, 1, 0); STH(1, 0, 0); STH(1, 1, 0);
  STH(0, 0, 1); STH(0, 1, 1); STH(1, 0, 1); STH(1, 1, 1);
  asm volatile("s_waitcnt vmcnt(8)" ::: "memory");
  __builtin_amdgcn_s_barrier();
  __builtin_amdgcn_sched_barrier(0);

#pragma unroll
  for (int i = 0; i < 4; ++i) {
    const int t0 = 2 * i, t1 = 2 * i + 1;
    const int b0 = 0, b1 = 1;
    RD_A(b0, 0); RD_B(b0, 0, bbA);
    if (i > 0) STH(1, 1, t1);
    asm volatile("s_waitcnt lgkmcnt(8)" ::: "memory");
    MIDBAR();
    MF(0, 0, bbA);
    ENDBAR();
    RD_B(b0, 1, bbB);
    if (i > 0) STH(0, 1, t1);
    MIDBAR();
    MF(0, 1, bbB);
    ENDBAR();
    RD_A(b0, 1);
    if (i < 3) STH(1, 0, t0 + 2);
    MIDBAR();
    MF(1, 1, bbB);
    ENDBAR();
    if (i < 3) STH(0, 0, t0 + 2);
    MIDBAR();
    MF(1, 0, bbA);
    if (i < 3) { asm volatile("s_waitcnt vmcnt(4)" ::: "memory"); }
    else       { asm volatile("s_waitcnt vmcnt(0)" ::: "memory"); }
    ENDBAR();
    RD_A(b1, 0); RD_B(b1, 0, bbA);
    if (i < 3) STH(1, 1, t0 + 2);
    asm volatile("s_waitcnt lgkmcnt(8)" ::: "memory");
    MIDBAR();
    MF(0, 0, bbA);
    ENDBAR();
    RD_B(b1, 1, bbB);
    if (i < 3) STH(0, 1, t0 + 2);
    MIDBAR();
    MF(0, 1, bbB);
    ENDBAR();
    RD_A(b1, 1);
    if (i < 3) STH(1, 0, t1 + 2);
    MIDBAR();
    MF(1, 1, bbB);
    ENDBAR();
    if (i < 3) STH(0, 0, t1 + 2);
    MIDBAR();
    MF(1, 0, bbA);
    if (i < 3) { asm volatile("s_waitcnt vmcnt(4)" ::: "memory"); }
    ENDBAR();
  }

#pragma unroll
  for (int mf = 0; mf < 8; ++mf) {
    f32x4 bv = *(const f32x4*)(bias + M0 + wr * 128 + mf * 16 + lq * 4);
#pragma unroll
    for (int nf = 0; nf < 4; ++nf) acc[mf][nf] += bv;
  }

  __syncthreads();
  if (M0 < 1024) {
    unsigned short* Ct = smem;
    for (int h2 = 0; h2 < 2; ++h2) {
      __syncthreads();
      if ((wc >> 1) == h2) {
        int ncb = (wc & 1) * 64;
#pragma unroll
        for (int mf = 0; mf < 8; ++mf)
#pragma unroll
          for (int nf = 0; nf < 4; ++nf) {
            int n = ncb + nf * 16 + lr;
            int m = wr * 128 + mf * 16 + lq * 4;
            ushort4 pk;
            pk.x = f2bf(acc[mf][nf].x); pk.y = f2bf(acc[mf][nf].y);
            pk.z = f2bf(acc[mf][nf].z); pk.w = f2bf(acc[mf][nf].w);
            *(ushort4*)(Ct + n * 264 + m) = pk;
          }
      }
      __syncthreads();
      int n = tid >> 2, q = tid & 3;
      const unsigned short* src = Ct + n * 264 + q * 64;
      unsigned short* dst = qk_t + (N0 + h2 * 128 + n) * 1024 + M0 + q * 64;
#pragma unroll
      for (int ch = 0; ch < 8; ++ch)
        *(uint4*)(dst + ch * 8) = *(const uint4*)(src + ch * 8);
    }
  } else {
#pragma unroll
    for (int mf = 0; mf < 8; ++mf)
#pragma unroll
      for (int nf = 0; nf < 4; ++nf) {
        int m = M0 - 1024 + wr * 128 + mf * 16 + lq * 4;
        size_t n = N0 + wc * 64 + nf * 16 + lr;
#pragma unroll
        for (int r = 0; r < 4; ++r)
          v_nat[(size_t)(m + r) * NPIX + n] = f2bf(acc[mf][nf][r]);
      }
  }
}

// ------------- attention v2: one block per (h, fixed), 32x32x16 MFMA --------
// 8 waves x 32 queries = 256 queries (whole row). Per wave:
//   S^T[j][i] = mfma32(K-frag, Q-frag)  (i = lane&31, j over 8 jt tiles)
//   softmax over j: 128 in-lane + 1 shfl_xor(32)
//   P-frags built IN-REGISTER: elem e of frag kt = S-reg r=(e&3)+4(2(kt&1)+hi)
//     from lane-half (e>>2)  ->  4 cvt_pk + 2 shfl_xor(32) per kt
//   O^T[i][d] = mfma32(P-frag, V-frag)  (V read from natural [d][j] LDS)
// PHASE 0: out1 = x + O (float4 stores) + out1^T bf16 via LDS transpose
// PHASE 1: colout_bt[c][fix*256+i] = bf16(O)  (ushort4 stores)
template <int PHASE>
__global__ __launch_bounds__(512) void k_attn2(const unsigned short* __restrict__ qk_t,
                                               const unsigned short* __restrict__ v_nat,
                                               const float* __restrict__ x,
                                               float* __restrict__ out1,
                                               unsigned short* __restrict__ out_bt) {
  __shared__ unsigned short smem[32768];      // 64 KiB: K^T 32K | V 32K; later Obt
  unsigned short* Ks = smem;                  // K^T [256 j][64 c], XOR-swizzled
  unsigned short* Vs = smem + 16384;          // V   [64 d][256 j], XOR-swizzled
  const int tid = threadIdx.x;
  const int lane = tid & 63, wave = tid >> 6;
  const int l31 = lane & 31, hi = lane >> 5;
  const int fix = blockIdx.x, h = blockIdx.y;
  const size_t pixbase = (size_t)fix * 256;
  const int i0w = wave * 32;

  // stage K^T (cols 512 + h*64 of qk_t rows)
#pragma unroll
  for (int it = 0; it < 4; ++it) {
    int f = it * 512 + tid;
    int j = f >> 3, ch = f & 7;
    uint4 val = *(const uint4*)(qk_t + (pixbase + j) * 1024 + 512 + h * 64 + ch * 8);
    *(uint4*)((char*)Ks + j * 128 + ((ch * 16) ^ ((j & 7) << 4))) = val;
  }
  // stage V
#pragma unroll
  for (int it = 0; it < 4; ++it) {
    int f = it * 512 + tid;
    int d = f >> 5, c2 = f & 31;
    uint4 val = *(const uint4*)(v_nat + (size_t)(h * 64 + d) * NPIX + pixbase + c2 * 8);
    *(uint4*)((char*)Vs + d * 512 + ((c2 * 16) ^ ((d & 7) << 4))) = val;
  }
  // Q fragments (B-operand): lane(hi, i=l31) holds Q[c = ks*16 + hi*8 + e][i]
  bf16x8 qf[4];
  {
    const unsigned short* qp = qk_t + (pixbase + i0w + l31) * 1024 + h * 64 + hi * 8;
#pragma unroll
    for (int ks = 0; ks < 4; ++ks) qf[ks] = *(const bf16x8*)(qp + ks * 16);
  }
  __syncthreads();

  // QK^T
  f32x16 s[8] = {};
  const int swz = (l31 & 7) << 4;
  __builtin_amdgcn_s_setprio(1);
#pragma unroll
  for (int jt = 0; jt < 8; ++jt) {
    const char* kr = (const char*)Ks + (jt * 32 + l31) * 128;
#pragma unroll
    for (int ks = 0; ks < 4; ++ks) {
      bf16x8 kf = *(const bf16x8*)(kr + ((ks * 32 + hi * 16) ^ swz));
      s[jt] = __builtin_amdgcn_mfma_f32_32x32x16_bf16(kf, qf[ks], s[jt], 0, 0, 0);
    }
  }
  __builtin_amdgcn_s_setprio(0);

  // softmax over j (row i = l31; 128 values in-lane, partner half has the rest)
  float mx = -3.4e38f;
#pragma unroll
  for (int jt = 0; jt < 8; ++jt)
#pragma unroll
    for (int r = 0; r < 16; ++r) mx = fmaxf(mx, s[jt][r]);
  mx = fmaxf(mx, __shfl_xor(mx, 32, 64));
  float sum = 0.f;
#pragma unroll
  for (int jt = 0; jt < 8; ++jt)
#pragma unroll
    for (int r = 0; r < 16; ++r) {
      float p = __expf(s[jt][r] - mx);
      s[jt][r] = p; sum += p;
    }
  sum += __shfl_xor(sum, 32, 64);
  float inv = 1.f / sum;

  // P fragments (A-operand for PV), normalized, in-register regroup
  bf16x8 pf[16];
#pragma unroll
  for (int jt = 0; jt < 8; ++jt)
#pragma unroll
    for (int kb = 0; kb < 2; ++kb) {
      int kt = jt * 2 + kb;
      unsigned pA0 = cvtpk(s[jt][kb * 8 + 0] * inv, s[jt][kb * 8 + 1] * inv);
      unsigned pA1 = cvtpk(s[jt][kb * 8 + 2] * inv, s[jt][kb * 8 + 3] * inv);
      unsigned pB0 = cvtpk(s[jt][kb * 8 + 4] * inv, s[jt][kb * 8 + 5] * inv);
      unsigned pB1 = cvtpk(s[jt][kb * 8 + 6] * inv, s[jt][kb * 8 + 7] * inv);
      // half-0 sends its B-quad (needed by hi=1 targets); half-1 sends its A-quad
      unsigned s0 = hi ? pA0 : pB0;
      unsigned s1 = hi ? pA1 : pB1;
      unsigned r0 = (unsigned)__shfl_xor((int)s0, 32, 64);
      unsigned r1 = (unsigned)__shfl_xor((int)s1, 32, 64);
      union { unsigned u[4]; bf16x8 v; } pk_;
      pk_.u[0] = hi ? r0 : pA0;   // e0,e1 (from half-0, quad 2kb+hi)
      pk_.u[1] = hi ? r1 : pA1;   // e2,e3
      pk_.u[2] = hi ? pB0 : r0;   // e4,e5 (from half-1, quad 2kb+hi)
      pk_.u[3] = hi ? pB1 : r1;   // e6,e7
      pf[kt] = pk_.v;
    }

  // PV: O^T[i][d]
  f32x16 o[2] = {};
  __builtin_amdgcn_s_setprio(1);
#pragma unroll
  for (int dt = 0; dt < 2; ++dt) {
    const char* vr = (const char*)Vs + (dt * 32 + l31) * 512;
#pragma unroll
    for (int kt = 0; kt < 16; ++kt) {
      bf16x8 vf = *(const bf16x8*)(vr + ((kt * 32 + hi * 16) ^ swz));
      o[dt] = __builtin_amdgcn_mfma_f32_32x32x16_bf16(pf[kt], vf, o[dt], 0, 0, 0);
    }
  }
  __builtin_amdgcn_s_setprio(0);

  // epilogue: lane(hi, d=dt*32+l31) holds O^T[i = q*8 + hi*4 + m][d], reg 4q+m
  if (PHASE == 0) {
#pragma unroll
    for (int dt = 0; dt < 2; ++dt) {
      int c = h * 64 + dt * 32 + l31;
      float* ob = out1 + (size_t)c * NPIX + pixbase + i0w;
      const float* xb = x + (size_t)c * NPIX + pixbase + i0w;
#pragma unroll
      for (int q = 0; q < 4; ++q) {
        int ib = q * 8 + hi * 4;
        float4 xv = *(const float4*)(xb + ib);
        float4 vv;
        vv.x = o[dt][q * 4 + 0] + xv.x;
        vv.y = o[dt][q * 4 + 1] + xv.y;
        vv.z = o[dt][q * 4 + 2] + xv.z;
        vv.w = o[dt][q * 4 + 3] + xv.w;
        *(float4*)(ob + ib) = vv;
        o[dt][q * 4 + 0] = vv.x; o[dt][q * 4 + 1] = vv.y;
        o[dt][q * 4 + 2] = vv.z; o[dt][q * 4 + 3] = vv.w;
      }
    }
    __syncthreads();                       // K/V reads done -> overlay Obt
    unsigned short* Obt = smem;            // [256 i][72 d] (72 for 16B-aligned rows)
#pragma unroll
    for (int dt = 0; dt < 2; ++dt) {
      int d = dt * 32 + l31;
#pragma unroll
      for (int q = 0; q < 4; ++q)
#pragma unroll
        for (int m = 0; m < 4; ++m)
          Obt[(i0w + q * 8 + hi * 4 + m) * 72 + d] = f2bf(o[dt][q * 4 + m]);
    }
    __syncthreads();
    int row = tid >> 1, half = tid & 1;
    const unsigned short* src = Obt + row * 72 + half * 32;
    unsigned short* dst = out_bt + ((size_t)row * 256 + fix) * 512 + h * 64 + half * 32;
#pragma unroll
    for (int c4 = 0; c4 < 4; ++c4)
      *(uint4*)(dst + c4 * 8) = *(const uint4*)(src + c4 * 8);
  } else {
#pragma unroll
    for (int dt = 0; dt < 2; ++dt) {
      int c = h * 64 + dt * 32 + l31;
      unsigned short* ob = out_bt + (size_t)c * NPIX + pixbase + i0w;
#pragma unroll
      for (int q = 0; q < 4; ++q) {
        ushort4 pkv;
        pkv.x = f2bf(o[dt][q * 4 + 0]);
        pkv.y = f2bf(o[dt][q * 4 + 1]);
        pkv.z = f2bf(o[dt][q * 4 + 2]);
        pkv.w = f2bf(o[dt][q * 4 + 3]);
        *(ushort4*)(ob + q * 8 + hi * 4) = pkv;
      }
    }
  }
}

// --------- final: out[c][s][l] += colout_bt[c][l][s] (LDS transpose-add) ----
__global__ __launch_bounds__(256) void k_final(const unsigned short* __restrict__ colt,
                                               float* __restrict__ out) {
  __shared__ unsigned short Xs[64 * 68];
  int c = blockIdx.y;
  int lt = blockIdx.x & 3, st = blockIdx.x >> 2;
  int l0 = lt * 64, s0 = st * 64;
  int t = threadIdx.x;
  for (int rep = 0; rep < 4; ++rep) {
    int f = rep * 256 + t, li = f >> 4, jj = f & 15;
    ushort4 v = *(const ushort4*)(colt + (size_t)c * NPIX + (size_t)(l0 + li) * 256 + s0 + jj * 4);
    *(ushort4*)(Xs + li * 68 + jj * 4) = v;
  }
  __syncthreads();
  int si = t >> 2, q = t & 3;
  float* drow = out + (size_t)c * NPIX + (size_t)(s0 + si) * 256 + l0 + q * 16;
  for (int h4 = 0; h4 < 4; ++h4) {
    float4 a = *(float4*)(drow + h4 * 4);
    a.x += bf2f(Xs[(q * 16 + h4 * 4 + 0) * 68 + si]);
    a.y += bf2f(Xs[(q * 16 + h4 * 4 + 1) * 68 + si]);
    a.z += bf2f(Xs[(q * 16 + h4 * 4 + 2) * 68 + si]);
    a.w += bf2f(Xs[(q * 16 + h4 * 4 + 3) * 68 + si]);
    *(float4*)(drow + h4 * 4) = a;
  }
}

extern "C" void kernel_launch(void* const* d_in, const int* in_sizes, int n_in,
                              void* d_out, int out_size, void* d_ws, size_t ws_size,
                              hipStream_t stream) {
  const float* x  = (const float*)d_in[0];
  const float* Wr = (const float*)d_in[1];
  const float* br = (const float*)d_in[2];
  const float* Wc = (const float*)d_in[3];
  const float* bc = (const float*)d_in[4];
  float* out = (float*)d_out;
  char* ws = (char*)d_ws;
  unsigned short* qk_t  = (unsigned short*)(ws);                            // 128 MB [65536][1024]
  unsigned short* v_nat = (unsigned short*)(ws + 134217728);                // 64 MB  [512][65536]
  unsigned short* scr3  = (unsigned short*)(ws + 134217728 + 67108864);     // 64 MB  x^T / out1bt / colout
  unsigned short* Wrb   = (unsigned short*)(ws + 268435456);                // 1.5 MB
  unsigned short* Wcb   = (unsigned short*)(ws + 268435456 + 1572864);      // 1.5 MB

  k_cvt<<<768, 256, 0, stream>>>(Wr, Wrb, 196608);
  k_cvt<<<768, 256, 0, stream>>>(Wc, Wcb, 196608);
  k_cvt_transpose<<<dim3(1024, 8), 256, 0, stream>>>(x, scr3);              // scr3 = x^T bf16
  k_gemm<<<dim3(6, 256), 512, 0, stream>>>(Wrb, scr3, br, qk_t, v_nat);     // row QKV
  k_attn2<0><<<dim3(256, 8), 512, 0, stream>>>(qk_t, v_nat, x, out, scr3);  // out=out1, scr3=out1^T bf16
  k_gemm<<<dim3(6, 256), 512, 0, stream>>>(Wcb, scr3, bc, qk_t, v_nat);     // col QKV
  k_attn2<1><<<dim3(256, 8), 512, 0, stream>>>(qk_t, v_nat, nullptr, nullptr, scr3); // scr3=colout
  k_final<<<dim3(16, 512), 256, 0, stream>>>(scr3, out);                    // out += colout^T
}